// Round 5
// baseline (298.205 us; speedup 1.0000x reference)
//
#include <hip/hip_runtime.h>
#include <stdint.h>
#include <math.h>

// S2Convolution: BATCH=8, FIN=64, FOUT=128, B_IN=32, B_OUT=16, NL=16, MDIM=31,
// grid 4x8=32, out [8,128,32,32,32] fp32.
//
// v9: k_zm + k_tr fused into k_zmt (kills the 134 MB Z3 HBM round-trip).
//   Block = (b, nd, l-half). Loops l over its 8-l chunk, same complex MFMA
//   GEMM as k_zm (one sign variant per block), scatters results into LDS
//   zout[m][o][l8], then flushes coalesced uint4 into z2 planes [mn][bo][l].
//   Zero-init zout reproduces k_tr's zero-fill for l < |n'| (incl. 16
//   flush-only blocks). B (khb row) double-buffered, 1 barrier per l-iter.
// Everything else unchanged from v8.

#define PI_D 3.14159265358979323846
#define SCALING_F 0.002762135864009951f   // 1/sqrt(32*64*16^4/32^2)

// ws offsets in 4-byte words.
#define OFF_WANA 0            // 16*31*64   = 31744  ([l][m][j] fp32)
#define OFF_FKR  31744        // 32*16*31   = 15872
#define OFF_FKI  47616        // 15872
#define OFF_D3   63488        // 253952 words = 507904 u16 bf16 [mn][k][hl][l]
#define OFF_XHAT 317440       // 16*31*8*64*2 = 507904
#define OFF_WT   317440       // 2048 words = 4096 f16 twiddles (dead xhat rows 0-1)
#define OFF_KHC  825344       // khb bf16 pairs: 136*128*64 = 1114112 u32 words
#define OFF_Z2   3053568      // 2 planes x 496*1024*16 bf16 = 8126464 words ([re|im][mn][bo][l])
#define OFF_T    11180032     // 32768*16*32  = 16777216 u32 (t bf16-pairs)
// total = 27957248 words = 112 MB

typedef unsigned short u16t;
typedef __attribute__((ext_vector_type(8))) short s8v;       // 8 bf16
typedef __attribute__((ext_vector_type(8))) _Float16 h8v;    // 8 f16
typedef __attribute__((ext_vector_type(4))) float f4v;

union frg { uint4 u; uint32_t w[4]; s8v s; h8v h; };

__device__ inline double ipow_d(double x, int e){
  double r = 1.0;
  while (e > 0){ if (e & 1) r *= x; x *= x; e >>= 1; }
  return r;
}

// Wigner small-d d^l_{m1,m2}(beta), fp64, matches reference _wigner_d
__device__ double wig_d(int l, int m1, int m2, double beta, const double* LF){
  double c = cos(0.5*beta), s = sin(0.5*beta);
  double sum = 0.0;
  for (int k = 0; k <= 2*l; ++k){
    int a1 = l + m2 - k, a3 = m1 - m2 + k, a4 = l - m1 - k;
    if (a1 < 0 || a3 < 0 || a4 < 0) continue;
    double logc = 0.5*(LF[l+m1]+LF[l-m1]+LF[l+m2]+LF[l-m2]) - LF[a1] - LF[k] - LF[a3] - LF[a4];
    double t = exp(logc) * ipow_d(c, a1 + a4) * ipow_d(s, a3 + k);
    sum += (a3 & 1) ? -t : t;  // (-1)^(m1-m2+k)
  }
  return sum;
}

__device__ inline uint32_t f2bf(float f){
  uint32_t u = __float_as_uint(f);
  return (u + 0x7fffu + ((u >> 16) & 1u)) >> 16;   // RNE
}
__device__ inline float bf2f(uint32_t h){ return __uint_as_float((h & 0xffffu) << 16); }
__device__ inline float bf2f_lo(uint32_t h){ return __uint_as_float(h << 16); }
__device__ inline float bf2f_hi(uint32_t h){ return __uint_as_float(h & 0xffff0000u); }
__device__ inline uint32_t pack2(float a, float b){ return f2bf(a) | (f2bf(b) << 16); }

#define LF_INIT \
  __shared__ double LF[40]; \
  if (threadIdx.x == 0){ LF[0] = 0.0; double acc_ = 0.0; for (int n_ = 1; n_ < 40; ++n_){ acc_ += log((double)n_); LF[n_] = acc_; } } \
  __syncthreads();

// zero D3B (so dense l-dots see 0 in invalid slots). 248 blocks x 256 x float4.
__global__ void k_zero(float* __restrict__ ws){
  int id = blockIdx.x*256 + threadIdx.x;
  *reinterpret_cast<float4*>(ws + OFF_D3 + (size_t)id*4) = make_float4(0.f,0.f,0.f,0.f);
}

// Merged constant tables: blocks [0,124) wana, [124,186) fk, [186,698) dsyn->D3B, 698 Wt.
__global__ void k_consts(float* __restrict__ ws){
  LF_INIT
  int bid = blockIdx.x, tid = threadIdx.x;
  if (bid < 124){
    // Driscoll-Healy weights: wsum depends only on j; each block spans <=2 j.
    __shared__ double wj2[2];
    int id0 = bid*256;
    int jbase = id0/496;
    if (tid < 2){
      int j = jbase + tid;
      double wv_ = 0.0;
      if (j < 64){
        double beta = PI_D*(2*j + 0.5)/128.0;
        double wsum = 0.0;
        for (int kk = 0; kk < 32; ++kk) wsum += sin(beta*(2*kk+1))/(double)(2*kk+1);
        wv_ = (2.0*PI_D/64.0)*(2.0/32.0)*sin(beta)*wsum;
      }
      wj2[tid] = wv_;
    }
    __syncthreads();
    int id = id0 + tid;
    int m = id % 31, l = (id / 31) & 15, j = id / 496;
    int mp = m - 15, amp = mp < 0 ? -mp : mp;
    float val = 0.f;
    if (amp <= l){
      double beta = PI_D*(2*j + 0.5)/128.0;
      val = (float)(wj2[j - jbase] * wig_d(l, mp, 0, beta, LF));
    }
    ws[OFF_WANA + (l*31 + m)*64 + j] = val;   // [l][m][j]
  } else if (bid < 186){
    int id = (bid - 124)*256 + tid;
    if (id >= 15872) return;
    int n = id % 31, l = (id / 31) & 15, g = id / 496;
    int np = n - 15, anp = np < 0 ? -np : np;
    float vr = 0.f, vi = 0.f;
    if (anp <= l){
      double beta = PI_D*((double)((g >> 3) + 1))/32.0;
      double alpha = (PI_D/4.0)*(double)(g & 7);
      double d = wig_d(l, np, 0, beta, LF);
      vr = (float)(d*cos(np*alpha));
      vi = (float)(d*sin(np*alpha));
    }
    ws[OFF_FKR + id] = vr;
    ws[OFF_FKI + id] = vi;
  } else if (bid < 698){
    // D3B[mn][k][hl][l] bf16 hi/lo: (2l+1)*wig_d in B-fragment layout.
    int bb = bid - 186;
    int k = bb >> 4, l = bb & 15;
    int n21 = 2*l + 1, items = (l+1)*n21;
    double beta = PI_D*(2*k + 0.5)/64.0;
    float fl = (float)(2*l + 1);
    u16t* d3b = reinterpret_cast<u16t*>(ws + OFF_D3);
    for (int item = tid; item < items; item += 256){
      int im = item / n21, in = item - (item/n21)*n21;
      int mn = im*31 + in - l + 15;
      float v = fl * (float)wig_d(l, im, in - l, beta, LF);
      uint32_t hb = f2bf(v);
      uint32_t lb = f2bf(v - bf2f(hb));
      d3b[(mn*32 + k)*32 + l]      = (u16t)hb;
      d3b[(mn*32 + k)*32 + 16 + l] = (u16t)lb;
    }
  } else {
    // Wt[nt][p][h][c][kidx] f16: B-fragment twiddles for the n-DFT.
    u16t* wt = reinterpret_cast<u16t*>(ws + OFF_WT);
    for (int idx = tid; idx < 4096; idx += 256){
      int kidx = idx & 31, cc = (idx >> 5) & 15, h = (idx >> 9) & 1;
      int p = (idx >> 10) & 1, nt = (idx >> 11) & 1;
      int q = kidx & 1, nloc = kidx >> 1, n = h*16 + nloc, cg = nt*16 + cc;
      float val = 0.f;
      if (n <= 30){
        double th = 2.0*PI_D*(double)(((17 + n)*cg) & 31)/32.0;
        float wr = (float)cos(th), wi = (float)sin(th);
        val = p ? (q ? wr : wi) : (q ? -wi : wr);
      }
      union { _Float16 hh[2]; u16t us[2]; } cv;
      cv.hh[0] = (_Float16)val; cv.hh[1] = (_Float16)0.f;
      wt[idx] = cv.us[0];
    }
  }
}

// xhat[l][m=15+m'][b][i] (cpx fp32), only m'>=0 rows (row>=15; rows 0-14 dead)
__global__ void k_xhat(const float* __restrict__ x, float* __restrict__ ws){
  __shared__ float xl[4096];
  __shared__ float c64[64], s64[64];
  __shared__ float xmr[1024], xmi[1024];
  int tid = threadIdx.x;
  int b = blockIdx.x >> 6, i = blockIdx.x & 63;
  const float* xp = x + (b*64 + i)*4096;
  for (int idx = tid; idx < 4096; idx += 256) xl[idx] = xp[idx];
  if (tid < 64){ double a = 2.0*PI_D*tid/64.0; c64[tid] = (float)cos(a); s64[tid] = (float)sin(a); }
  __syncthreads();
  for (int item = tid; item < 1024; item += 256){
    int j = item >> 4, mi = item & 15;
    float re = 0.f, im = 0.f;
    const float* xr = xl + j*64;
    for (int a = 0; a < 64; ++a){
      int p = (mi*a) & 63;
      re += xr[a]*c64[p];
      im -= xr[a]*s64[p];
    }
    xmr[item] = re; xmi[item] = im;
  }
  __syncthreads();
  {
    int l = tid >> 4, mi = tid & 15;
    if (mi <= l){
      float rr = 0.f, ri = 0.f;
      const float* wrow = ws + OFF_WANA + (l*31 + 15 + mi)*64;   // dense j-row
      for (int j = 0; j < 64; ++j){
        float w = wrow[j];
        rr += w * xmr[j*16 + mi];
        ri += w * xmi[j*16 + mi];
      }
      int dst = OFF_XHAT + ((l*31 + 15 + mi)*8 + b)*128 + i*2;
      ws[dst] = rr; ws[dst+1] = ri;
    }
  }
}

// khb[row=tri(l)+np][o][i] u32 = (bf16 re, bf16 im) of
//   SCALING * sum_g kernel[i,o,g] * conj(FK[g,l,15+np]), np in [0,l]
__global__ void k_khc(const float* __restrict__ kern, float* __restrict__ ws){
  __shared__ float kl2[32*66];
  __shared__ float fr[992], fi[992];
  int tid = threadIdx.x;
  int o = blockIdx.x >> 4, l = blockIdx.x & 15;
  for (int idx = tid; idx < 2048; idx += 256){
    int i = idx >> 5, g = idx & 31;
    kl2[g*66 + i] = kern[(i*128 + o)*32 + g];
  }
  for (int idx = tid; idx < 992; idx += 256){
    int g = idx / 31, n = idx - (idx/31)*31;
    fr[idx] = ws[OFF_FKR + g*496 + l*31 + n];
    fi[idx] = ws[OFF_FKI + g*496 + l*31 + n];
  }
  __syncthreads();
  uint32_t* khb = reinterpret_cast<uint32_t*>(ws + OFF_KHC);
  int c1 = (l*(l+1)) >> 1;
  int ntask = (l+1)*32;
  for (int t = tid; t < ntask; t += 256){
    int np = t >> 5, ip = t & 31, i0 = 2*ip;
    float ar0=0.f, ai0=0.f, ar1=0.f, ai1=0.f;
    for (int g = 0; g < 32; ++g){
      float2 kv = *reinterpret_cast<const float2*>(kl2 + g*66 + i0);
      float fv = fr[g*31 + 15 + np], gv = fi[g*31 + 15 + np];
      ar0 += kv.x*fv; ai0 -= kv.x*gv;
      ar1 += kv.y*fv; ai1 -= kv.y*gv;
    }
    size_t base = (size_t)((c1 + np)*128 + o)*64 + i0;
    khb[base]     = pack2(SCALING_F*ar0, SCALING_F*ai0);
    khb[base + 1] = pack2(SCALING_F*ar1, SCALING_F*ai1);
  }
}

// Fused MFMA z + transpose. Block = (b, nd, l-half). 512 threads = 8 waves.
// Per l in chunk: z[m16][o128] = sum_i xhat[l,m,b,i]*khb-variant (same MFMA
// math as verified k_zm, one sign per block). Results scattered into LDS
// zout[m][o][l8], flushed coalesced into z2 planes [mn][bo][l]. zout
// zero-init covers l<|n'| slots (incl. flush-only blocks).
__device__ inline int zswz(int o){ return (o ^ (o >> 3)) & 7; }

__global__ __launch_bounds__(512) void k_zmt(float* __restrict__ ws){
  __shared__ uint32_t lb[2][9216];   // per buf: B[o128][i64] swz (8192) + A[m16][i64] swz (1024)
  __shared__ uint32_t zout[16384];   // [m16][o128][l8] u32 (re,im), swz lq^zswz(o)
  int tid = threadIdx.x, lane = tid & 63, wv = tid >> 6;
  int c = lane & 15, g = lane >> 4;
  int bid = blockIdx.x;
  int b = bid / 62, t = bid - b*62;
  int nd = t >> 1, h = t & 1;
  int ndp = nd - 15, a = ndp < 0 ? -ndp : ndp;
  int neg = ndp < 0;
  int l_lo = a > 8*h ? a : 8*h;
  int l_hi = 8*h + 7;

  for (int i = tid; i < 16384; i += 512) zout[i] = 0u;

  const uint32_t* khb = reinterpret_cast<const uint32_t*>(ws + OFF_KHC);

  // prologue: stage l_lo into buf 0
  if (l_lo <= l_hi){
    size_t rowb = (size_t)((l_lo*(l_lo+1))/2 + a)*128;
    #pragma unroll
    for (int t4 = 0; t4 < 4; ++t4){
      int idx4 = t4*512 + tid;
      int o = idx4 >> 4, i4 = idx4 & 15;
      uint4 v = *reinterpret_cast<const uint4*>(khb + (rowb + o)*64 + i4*4);
      *reinterpret_cast<uint4*>(lb[0] + ((o*64 + i4*4) ^ ((o & 7) << 2))) = v;
    }
    int m = tid >> 5, i0 = (tid & 31)*2;
    uint32_t a0 = 0u, a1 = 0u;
    if (m <= l_lo){
      float4 xv = *reinterpret_cast<const float4*>(ws + OFF_XHAT + (((l_lo*31 + 15 + m)*8 + b)*128 + i0*2));
      a0 = pack2(xv.x, xv.y); a1 = pack2(xv.z, xv.w);
    }
    int ai_ = (m*64 + i0) ^ ((m & 7) << 2);
    lb[0][8192 + ai_] = a0; lb[0][8192 + ai_ + 1] = a1;
  }
  __syncthreads();

  int cur = 0;
  for (int l = l_lo; l <= l_hi; ++l){
    // prefetch l+1 into registers
    uint4 pB[4]; float4 pA = make_float4(0.f,0.f,0.f,0.f);
    int pm = tid >> 5, pi0 = (tid & 31)*2;
    bool pf = (l < l_hi);
    if (pf){
      int lx = l + 1;
      size_t rowb = (size_t)((lx*(lx+1))/2 + a)*128;
      #pragma unroll
      for (int t4 = 0; t4 < 4; ++t4){
        int idx4 = t4*512 + tid;
        int o = idx4 >> 4, i4 = idx4 & 15;
        pB[t4] = *reinterpret_cast<const uint4*>(khb + (rowb + o)*64 + i4*4);
      }
      if (pm <= lx)
        pA = *reinterpret_cast<const float4*>(ws + OFF_XHAT + (((lx*31 + 15 + pm)*8 + b)*128 + pi0*2));
    }
    // compute current l
    uint32_t* B = lb[cur];
    uint32_t* A = lb[cur] + 8192;
    frg af[4];
    #pragma unroll
    for (int tt = 0; tt < 4; ++tt)
      af[tt].u = *reinterpret_cast<const uint4*>(A + ((c*64 + tt*16 + g*4) ^ ((c & 7) << 2)));
    int oc = wv*16 + c;
    f4v ar = {0.f,0.f,0.f,0.f}, ai = {0.f,0.f,0.f,0.f};
    #pragma unroll
    for (int tt = 0; tt < 4; ++tt){
      frg bw;
      bw.u = *reinterpret_cast<const uint4*>(B + ((oc*64 + tt*16 + g*4) ^ ((oc & 7) << 2)));
      frg br_, bi_;
      #pragma unroll
      for (int j = 0; j < 4; ++j){
        uint32_t w = bw.w[j];
        uint32_t sw = (w >> 16) | (w << 16);
        if (!neg){ br_.w[j] = w ^ 0x80000000u; bi_.w[j] = sw; }
        else if (a & 1){ br_.w[j] = w ^ 0x80008000u; bi_.w[j] = sw ^ 0x80000000u; }
        else { br_.w[j] = w; bi_.w[j] = sw ^ 0x00008000u; }
      }
      ar = __builtin_amdgcn_mfma_f32_16x16x32_bf16(af[tt].s, br_.s, ar, 0, 0, 0);
      ai = __builtin_amdgcn_mfma_f32_16x16x32_bf16(af[tt].s, bi_.s, ai, 0, 0, 0);
    }
    int lq = l - 8*h;
    #pragma unroll
    for (int rr = 0; rr < 4; ++rr){
      int m = g*4 + rr;   // C row=(lane>>4)*4+reg, col=lane&15 (=o within tile)
      zout[(m*128 + oc)*8 + (lq ^ zswz(oc))] = pack2(ar[rr], ai[rr]);
    }
    // commit prefetch to alt buffer
    if (pf){
      uint32_t* D = lb[cur ^ 1];
      #pragma unroll
      for (int t4 = 0; t4 < 4; ++t4){
        int idx4 = t4*512 + tid;
        int o = idx4 >> 4, i4 = idx4 & 15;
        *reinterpret_cast<uint4*>(D + ((o*64 + i4*4) ^ ((o & 7) << 2))) = pB[t4];
      }
      int ai_ = (pm*64 + pi0) ^ ((pm & 7) << 2);
      uint32_t a0 = 0u, a1 = 0u;
      if (pm <= l + 1){ a0 = pack2(pA.x, pA.y); a1 = pack2(pA.z, pA.w); }
      D[8192 + ai_] = a0; D[8192 + ai_ + 1] = a1;
    }
    __syncthreads();
    cur ^= 1;
  }

  // flush zout -> z2 planes
  u16t* zr = reinterpret_cast<u16t*>(ws + OFF_Z2);
  u16t* zi = zr + 8126464;
  for (int idx = tid; idx < 2048; idx += 512){
    int m = idx >> 7, o = idx & 127;
    uint32_t v[8];
    #pragma unroll
    for (int lq = 0; lq < 8; ++lq) v[lq] = zout[(m*128 + o)*8 + (lq ^ zswz(o))];
    uint4 reQ = make_uint4((v[0]&0xffffu)|(v[1]<<16), (v[2]&0xffffu)|(v[3]<<16),
                           (v[4]&0xffffu)|(v[5]<<16), (v[6]&0xffffu)|(v[7]<<16));
    uint4 imQ = make_uint4((v[0]>>16)|(v[1]&0xffff0000u), (v[2]>>16)|(v[3]&0xffff0000u),
                           (v[4]>>16)|(v[5]&0xffff0000u), (v[6]>>16)|(v[7]&0xffff0000u));
    size_t base = (size_t)(m*31 + nd)*16384 + (size_t)(b*128 + o)*16 + h*8;
    *reinterpret_cast<uint4*>(zr + base) = reQ;
    *reinterpret_cast<uint4*>(zi + base) = imQ;
  }
}

// MFMA fm+DFT. Block = (bo-tile of 16) x (m). 512 threads.
__global__ __launch_bounds__(512) void k_fmt(float* __restrict__ ws){
  __shared__ uint32_t fmb[16384];       // [nd 32][bok 512] u32 (f16 re,im), swz
  int tid = threadIdx.x;
  int lane = tid & 63, wv = tid >> 6;
  int c = lane & 15, g = lane >> 4;
  int bt = blockIdx.x >> 4, m = blockIdx.x & 15;
  const u16t* z2r = reinterpret_cast<const u16t*>(ws + OFF_Z2);
  const u16t* z2i = z2r + 8126464;
  const u16t* d3b = reinterpret_cast<const u16t*>(ws + OFF_D3);
  const u16t* wtb = reinterpret_cast<const u16t*>(ws + OFF_WT);
  fmb[31*512 + (tid ^ 16)] = 0u;   // zero-pad nd=31 column

  frg wf[2][2][2];
  #pragma unroll
  for (int nt = 0; nt < 2; ++nt)
    #pragma unroll
    for (int p = 0; p < 2; ++p)
      #pragma unroll
      for (int h = 0; h < 2; ++h)
        wf[nt][p][h].u = *reinterpret_cast<const uint4*>(wtb + ((((nt*2+p)*2+h)*16 + c)*32 + g*8));

  // ---- phase A ----
  {
    int l0 = (g & 1)*8;
    int hl16 = (g >> 1)*16;
    size_t bo16 = (size_t)(bt*16 + c)*16;
    #pragma unroll
    for (int t = 0; t < 4; ++t){
      int nd = wv*4 + t;
      if (nd > 30) break;
      int mn = m*31 + nd;
      frg ar, ai;
      ar.u = *reinterpret_cast<const uint4*>(z2r + (size_t)mn*16384 + bo16 + l0);
      ai.u = *reinterpret_cast<const uint4*>(z2i + (size_t)mn*16384 + bo16 + l0);
      int key = ((nd >> 2) & 1) << 4;
      #pragma unroll
      for (int kh = 0; kh < 2; ++kh){
        frg bf;
        bf.u = *reinterpret_cast<const uint4*>(d3b + ((size_t)mn*32 + kh*16 + c)*32 + hl16 + l0);
        f4v z4 = {0.f, 0.f, 0.f, 0.f};
        f4v cre = __builtin_amdgcn_mfma_f32_16x16x32_bf16(ar.s, bf.s, z4, 0, 0, 0);
        f4v cim = __builtin_amdgcn_mfma_f32_16x16x32_bf16(ai.s, bf.s, z4, 0, 0, 0);
        #pragma unroll
        for (int rr = 0; rr < 4; ++rr){
          int bok = (g*4 + rr)*32 + kh*16 + c;
          union { _Float16 hh[2]; uint32_t u; } pk;
          pk.hh[0] = (_Float16)cre[rr];
          pk.hh[1] = (_Float16)cim[rr];
          fmb[nd*512 + (bok ^ key)] = pk.u;
        }
      }
    }
  }
  __syncthreads();
  // ---- phase B ----
  uint32_t* tglob = reinterpret_cast<uint32_t*>(ws) + OFF_T;
  #pragma unroll
  for (int q = 0; q < 4; ++q){
    int mt = wv*4 + q;
    int arow = mt*16 + c;
    frg A0, A1;
    #pragma unroll
    for (int j = 0; j < 4; ++j){
      int nd0 = g*4 + j, nd1 = nd0 + 16;
      A0.w[j] = fmb[nd0*512 + (arow ^ (((nd0 >> 2) & 1) << 4))];
      A1.w[j] = fmb[nd1*512 + (arow ^ (((nd1 >> 2) & 1) << 4))];
    }
    #pragma unroll
    for (int nt = 0; nt < 2; ++nt){
      f4v z4 = {0.f, 0.f, 0.f, 0.f};
      f4v tre = __builtin_amdgcn_mfma_f32_16x16x32_f16(A0.h, wf[nt][0][0].h, z4, 0, 0, 0);
      tre     = __builtin_amdgcn_mfma_f32_16x16x32_f16(A1.h, wf[nt][0][1].h, tre, 0, 0, 0);
      f4v tim = __builtin_amdgcn_mfma_f32_16x16x32_f16(A0.h, wf[nt][1][0].h, z4, 0, 0, 0);
      tim     = __builtin_amdgcn_mfma_f32_16x16x32_f16(A1.h, wf[nt][1][1].h, tim, 0, 0, 0);
      #pragma unroll
      for (int rr = 0; rr < 4; ++rr){
        int bokl = mt*16 + g*4 + rr;
        int bokg = (bt*16 + (bokl >> 5))*32 + (bokl & 31);
        tglob[(size_t)(bokg*16 + m)*32 + nt*16 + c] = pack2(tre[rr], tim[rr]);
      }
    }
  }
}

// out[bok][a][c] = t0.re + sum_{m'=1..15} 2 Re(t[m',c] e^{i 2pi a m'/32}) + bias.
__global__ void k_out(const float* __restrict__ bias, float* __restrict__ out,
                      const float* __restrict__ ws){
  __shared__ uint32_t tl[2048];
  __shared__ float2 tw2[32];
  int tid = threadIdx.x;
  int b4 = blockIdx.x*4;
  const uint32_t* tg = reinterpret_cast<const uint32_t*>(ws) + OFF_T + (size_t)b4*512;
  for (int idx = tid; idx < 2048; idx += 256) tl[idx] = tg[idx];
  if (tid < 32){ double a = 2.0*PI_D*tid/32.0; tw2[tid] = make_float2((float)cos(a), (float)sin(a)); }
  __syncthreads();
  int aq = tid >> 5, c = tid & 31;
  for (int q = 0; q < 4; ++q){
    int bok = b4 + q;
    const uint32_t* tq = tl + q*512;
    float t0r = bf2f(tq[c]);
    float U0=0,U1=0,U2=0,U3=0,V0=0,V1=0,V2=0,V3=0;
    int p = aq;
    #pragma unroll
    for (int m = 1; m < 16; ++m){
      uint32_t wv = tq[m*32 + c];
      float tr = bf2f_lo(wv), ti = bf2f_hi(wv);
      float2 T = tw2[p];
      float u = tr*T.x - ti*T.y;
      float v = tr*T.y + ti*T.x;
      int j = m & 3;
      if      (j == 0){ U0 += u; V0 += v; }
      else if (j == 1){ U1 += u; V1 += v; }
      else if (j == 2){ U2 += u; V2 += v; }
      else            { U3 += u; V3 += v; }
      p = (p + aq) & 31;
    }
    float bia = bias[(bok >> 5) & 127];
    float* op = out + (size_t)bok*1024 + c;
    op[aq*32]      = t0r + 2.f*(U0+U1+U2+U3) + bia;
    op[(aq+8)*32]  = t0r + 2.f*(U0-V1-U2+V3) + bia;
    op[(aq+16)*32] = t0r + 2.f*(U0-U1+U2-U3) + bia;
    op[(aq+24)*32] = t0r + 2.f*(U0+V1-U2-V3) + bia;
  }
}

extern "C" void kernel_launch(void* const* d_in, const int* in_sizes, int n_in,
                              void* d_out, int out_size, void* d_ws, size_t ws_size,
                              hipStream_t stream) {
  const float* x    = (const float*)d_in[0];   // [8,64,64,64]
  const float* kern = (const float*)d_in[1];   // [64,128,32]
  const float* bias = (const float*)d_in[2];   // [128]
  float* out = (float*)d_out;                  // [8,128,32,32,32]
  float* ws  = (float*)d_ws;

  k_zero  <<<dim3(248),  dim3(256), 0, stream>>>(ws);
  k_consts<<<dim3(699),  dim3(256), 0, stream>>>(ws);
  k_xhat  <<<dim3(512),  dim3(256), 0, stream>>>(x, ws);
  k_khc   <<<dim3(2048), dim3(256), 0, stream>>>(kern, ws);
  k_zmt   <<<dim3(496),  dim3(512), 0, stream>>>(ws);
  k_fmt   <<<dim3(1024), dim3(512), 0, stream>>>(ws);
  k_out   <<<dim3(8192), dim3(256), 0, stream>>>(bias, out, ws);
}

// Round 6
// 284.864 us; speedup vs baseline: 1.0468x; 1.0468x over previous
//
#include <hip/hip_runtime.h>
#include <stdint.h>
#include <math.h>

// S2Convolution: BATCH=8, FIN=64, FOUT=128, B_IN=32, B_OUT=16, NL=16, MDIM=31,
// grid 4x8=32, out [8,128,32,32,32] fp32.
//
// v10: k_zmt v2 (fixes v9's 1-block/CU + write-amplification disaster).
//  - Block = (b, nd, l-half h, o-half oh); 256 thr; LDS 52 KB -> 3 blocks/CU.
//  - z2 planes re-laid as [mn][h][bo][l8] u16 (h sub-planes) -> flush writes
//    dense 1 KB runs (no 16B interleave RMW). k_fmt phase-A address updated.
//  - Single 20 KB stage buf (B o-half 16 KB + A 4 KB), register prefetch,
//    2 barriers/iter, up to 8 l-iters. Same MFMA math as verified k_zm.
// Everything else = v8 (263 us verified).

#define PI_D 3.14159265358979323846
#define SCALING_F 0.002762135864009951f   // 1/sqrt(32*64*16^4/32^2)

// ws offsets in 4-byte words.
#define OFF_WANA 0            // 16*31*64   = 31744  ([l][m][j] fp32)
#define OFF_FKR  31744        // 32*16*31   = 15872
#define OFF_FKI  47616        // 15872
#define OFF_D3   63488        // 253952 words = 507904 u16 bf16 [mn][k][hl][l]
#define OFF_XHAT 317440       // 16*31*8*64*2 = 507904
#define OFF_WT   317440       // 2048 words = 4096 f16 twiddles (dead xhat rows 0-1)
#define OFF_KHC  825344       // khb bf16 pairs: 136*128*64 = 1114112 u32 words
#define OFF_Z2   3053568      // 2 planes x 496*2*1024*8 bf16 = 8126464 words ([re|im][mn][h][bo][l8])
#define OFF_T    11180032     // 32768*16*32  = 16777216 u32 (t bf16-pairs)
// total = 27957248 words = 112 MB

typedef unsigned short u16t;
typedef __attribute__((ext_vector_type(8))) short s8v;       // 8 bf16
typedef __attribute__((ext_vector_type(8))) _Float16 h8v;    // 8 f16
typedef __attribute__((ext_vector_type(4))) float f4v;

union frg { uint4 u; uint32_t w[4]; s8v s; h8v h; };

__device__ inline double ipow_d(double x, int e){
  double r = 1.0;
  while (e > 0){ if (e & 1) r *= x; x *= x; e >>= 1; }
  return r;
}

// Wigner small-d d^l_{m1,m2}(beta), fp64, matches reference _wigner_d
__device__ double wig_d(int l, int m1, int m2, double beta, const double* LF){
  double c = cos(0.5*beta), s = sin(0.5*beta);
  double sum = 0.0;
  for (int k = 0; k <= 2*l; ++k){
    int a1 = l + m2 - k, a3 = m1 - m2 + k, a4 = l - m1 - k;
    if (a1 < 0 || a3 < 0 || a4 < 0) continue;
    double logc = 0.5*(LF[l+m1]+LF[l-m1]+LF[l+m2]+LF[l-m2]) - LF[a1] - LF[k] - LF[a3] - LF[a4];
    double t = exp(logc) * ipow_d(c, a1 + a4) * ipow_d(s, a3 + k);
    sum += (a3 & 1) ? -t : t;  // (-1)^(m1-m2+k)
  }
  return sum;
}

__device__ inline uint32_t f2bf(float f){
  uint32_t u = __float_as_uint(f);
  return (u + 0x7fffu + ((u >> 16) & 1u)) >> 16;   // RNE
}
__device__ inline float bf2f(uint32_t h){ return __uint_as_float((h & 0xffffu) << 16); }
__device__ inline float bf2f_lo(uint32_t h){ return __uint_as_float(h << 16); }
__device__ inline float bf2f_hi(uint32_t h){ return __uint_as_float(h & 0xffff0000u); }
__device__ inline uint32_t pack2(float a, float b){ return f2bf(a) | (f2bf(b) << 16); }

#define LF_INIT \
  __shared__ double LF[40]; \
  if (threadIdx.x == 0){ LF[0] = 0.0; double acc_ = 0.0; for (int n_ = 1; n_ < 40; ++n_){ acc_ += log((double)n_); LF[n_] = acc_; } } \
  __syncthreads();

// zero D3B (so dense l-dots see 0 in invalid slots). 248 blocks x 256 x float4.
__global__ void k_zero(float* __restrict__ ws){
  int id = blockIdx.x*256 + threadIdx.x;
  *reinterpret_cast<float4*>(ws + OFF_D3 + (size_t)id*4) = make_float4(0.f,0.f,0.f,0.f);
}

// Merged constant tables: blocks [0,124) wana, [124,186) fk, [186,698) dsyn->D3B, 698 Wt.
__global__ void k_consts(float* __restrict__ ws){
  LF_INIT
  int bid = blockIdx.x, tid = threadIdx.x;
  if (bid < 124){
    // Driscoll-Healy weights: wsum depends only on j; each block spans <=2 j.
    __shared__ double wj2[2];
    int id0 = bid*256;
    int jbase = id0/496;
    if (tid < 2){
      int j = jbase + tid;
      double wv_ = 0.0;
      if (j < 64){
        double beta = PI_D*(2*j + 0.5)/128.0;
        double wsum = 0.0;
        for (int kk = 0; kk < 32; ++kk) wsum += sin(beta*(2*kk+1))/(double)(2*kk+1);
        wv_ = (2.0*PI_D/64.0)*(2.0/32.0)*sin(beta)*wsum;
      }
      wj2[tid] = wv_;
    }
    __syncthreads();
    int id = id0 + tid;
    int m = id % 31, l = (id / 31) & 15, j = id / 496;
    int mp = m - 15, amp = mp < 0 ? -mp : mp;
    float val = 0.f;
    if (amp <= l){
      double beta = PI_D*(2*j + 0.5)/128.0;
      val = (float)(wj2[j - jbase] * wig_d(l, mp, 0, beta, LF));
    }
    ws[OFF_WANA + (l*31 + m)*64 + j] = val;   // [l][m][j]
  } else if (bid < 186){
    int id = (bid - 124)*256 + tid;
    if (id >= 15872) return;
    int n = id % 31, l = (id / 31) & 15, g = id / 496;
    int np = n - 15, anp = np < 0 ? -np : np;
    float vr = 0.f, vi = 0.f;
    if (anp <= l){
      double beta = PI_D*((double)((g >> 3) + 1))/32.0;
      double alpha = (PI_D/4.0)*(double)(g & 7);
      double d = wig_d(l, np, 0, beta, LF);
      vr = (float)(d*cos(np*alpha));
      vi = (float)(d*sin(np*alpha));
    }
    ws[OFF_FKR + id] = vr;
    ws[OFF_FKI + id] = vi;
  } else if (bid < 698){
    // D3B[mn][k][hl][l] bf16 hi/lo: (2l+1)*wig_d in B-fragment layout.
    int bb = bid - 186;
    int k = bb >> 4, l = bb & 15;
    int n21 = 2*l + 1, items = (l+1)*n21;
    double beta = PI_D*(2*k + 0.5)/64.0;
    float fl = (float)(2*l + 1);
    u16t* d3b = reinterpret_cast<u16t*>(ws + OFF_D3);
    for (int item = tid; item < items; item += 256){
      int im = item / n21, in = item - (item/n21)*n21;
      int mn = im*31 + in - l + 15;
      float v = fl * (float)wig_d(l, im, in - l, beta, LF);
      uint32_t hb = f2bf(v);
      uint32_t lb = f2bf(v - bf2f(hb));
      d3b[(mn*32 + k)*32 + l]      = (u16t)hb;
      d3b[(mn*32 + k)*32 + 16 + l] = (u16t)lb;
    }
  } else {
    // Wt[nt][p][h][c][kidx] f16: B-fragment twiddles for the n-DFT.
    u16t* wt = reinterpret_cast<u16t*>(ws + OFF_WT);
    for (int idx = tid; idx < 4096; idx += 256){
      int kidx = idx & 31, cc = (idx >> 5) & 15, h = (idx >> 9) & 1;
      int p = (idx >> 10) & 1, nt = (idx >> 11) & 1;
      int q = kidx & 1, nloc = kidx >> 1, n = h*16 + nloc, cg = nt*16 + cc;
      float val = 0.f;
      if (n <= 30){
        double th = 2.0*PI_D*(double)(((17 + n)*cg) & 31)/32.0;
        float wr = (float)cos(th), wi = (float)sin(th);
        val = p ? (q ? wr : wi) : (q ? -wi : wr);
      }
      union { _Float16 hh[2]; u16t us[2]; } cv;
      cv.hh[0] = (_Float16)val; cv.hh[1] = (_Float16)0.f;
      wt[idx] = cv.us[0];
    }
  }
}

// xhat[l][m=15+m'][b][i] (cpx fp32), only m'>=0 rows (row>=15; rows 0-14 dead)
__global__ void k_xhat(const float* __restrict__ x, float* __restrict__ ws){
  __shared__ float xl[4096];
  __shared__ float c64[64], s64[64];
  __shared__ float xmr[1024], xmi[1024];
  int tid = threadIdx.x;
  int b = blockIdx.x >> 6, i = blockIdx.x & 63;
  const float* xp = x + (b*64 + i)*4096;
  for (int idx = tid; idx < 4096; idx += 256) xl[idx] = xp[idx];
  if (tid < 64){ double a = 2.0*PI_D*tid/64.0; c64[tid] = (float)cos(a); s64[tid] = (float)sin(a); }
  __syncthreads();
  for (int item = tid; item < 1024; item += 256){
    int j = item >> 4, mi = item & 15;
    float re = 0.f, im = 0.f;
    const float* xr = xl + j*64;
    for (int a = 0; a < 64; ++a){
      int p = (mi*a) & 63;
      re += xr[a]*c64[p];
      im -= xr[a]*s64[p];
    }
    xmr[item] = re; xmi[item] = im;
  }
  __syncthreads();
  {
    int l = tid >> 4, mi = tid & 15;
    if (mi <= l){
      float rr = 0.f, ri = 0.f;
      const float* wrow = ws + OFF_WANA + (l*31 + 15 + mi)*64;   // dense j-row
      for (int j = 0; j < 64; ++j){
        float w = wrow[j];
        rr += w * xmr[j*16 + mi];
        ri += w * xmi[j*16 + mi];
      }
      int dst = OFF_XHAT + ((l*31 + 15 + mi)*8 + b)*128 + i*2;
      ws[dst] = rr; ws[dst+1] = ri;
    }
  }
}

// khb[row=tri(l)+np][o][i] u32 = (bf16 re, bf16 im) of
//   SCALING * sum_g kernel[i,o,g] * conj(FK[g,l,15+np]), np in [0,l]
__global__ void k_khc(const float* __restrict__ kern, float* __restrict__ ws){
  __shared__ float kl2[32*66];
  __shared__ float fr[992], fi[992];
  int tid = threadIdx.x;
  int o = blockIdx.x >> 4, l = blockIdx.x & 15;
  for (int idx = tid; idx < 2048; idx += 256){
    int i = idx >> 5, g = idx & 31;
    kl2[g*66 + i] = kern[(i*128 + o)*32 + g];
  }
  for (int idx = tid; idx < 992; idx += 256){
    int g = idx / 31, n = idx - (idx/31)*31;
    fr[idx] = ws[OFF_FKR + g*496 + l*31 + n];
    fi[idx] = ws[OFF_FKI + g*496 + l*31 + n];
  }
  __syncthreads();
  uint32_t* khb = reinterpret_cast<uint32_t*>(ws + OFF_KHC);
  int c1 = (l*(l+1)) >> 1;
  int ntask = (l+1)*32;
  for (int t = tid; t < ntask; t += 256){
    int np = t >> 5, ip = t & 31, i0 = 2*ip;
    float ar0=0.f, ai0=0.f, ar1=0.f, ai1=0.f;
    for (int g = 0; g < 32; ++g){
      float2 kv = *reinterpret_cast<const float2*>(kl2 + g*66 + i0);
      float fv = fr[g*31 + 15 + np], gv = fi[g*31 + 15 + np];
      ar0 += kv.x*fv; ai0 -= kv.x*gv;
      ar1 += kv.y*fv; ai1 -= kv.y*gv;
    }
    size_t base = (size_t)((c1 + np)*128 + o)*64 + i0;
    khb[base]     = pack2(SCALING_F*ar0, SCALING_F*ai0);
    khb[base + 1] = pack2(SCALING_F*ar1, SCALING_F*ai1);
  }
}

// Fused MFMA z + transpose, v2. Block = (b, nd, l-half h, o-half oh).
// 256 threads = 4 waves, each owning one o-tile of 16. LDS 52 KB -> 3 blk/CU.
// Per l in [max(a,8h), 8h+7]: z[m16][o64] complex MFMA (k_zm math, one sign
// variant per block), scattered into zout[m][o64][l8]; flushed dense into
// z2 sub-planes [mn][h][bo][l8]. zout zero-init covers l<|n'| slots.
__device__ inline int zswz(int o){ return (o ^ (o >> 3)) & 7; }

__global__ __launch_bounds__(256) void k_zmt(float* __restrict__ ws){
  __shared__ uint32_t sb[5120];     // B[o64][i64] swz (4096) + A[m16][i64] swz (1024)
  __shared__ uint32_t zout[8192];   // [m16][o64][l8] u32 (re,im), swz lq^zswz(o)
  int tid = threadIdx.x, lane = tid & 63, wv = tid >> 6;
  int c = lane & 15, g = lane >> 4;
  int bid = blockIdx.x;
  int b  = bid / 124;
  int r  = bid - b*124;
  int nd = r >> 2, h = (r >> 1) & 1, oh = r & 1;
  int ndp = nd - 15, a = ndp < 0 ? -ndp : ndp;
  int neg = ndp < 0;
  int l_lo = a > 8*h ? a : 8*h;
  int l_hi = 8*h + 7;

  for (int i4 = tid; i4 < 2048; i4 += 256)
    *reinterpret_cast<uint4*>(zout + i4*4) = make_uint4(0u,0u,0u,0u);

  const uint32_t* khb = reinterpret_cast<const uint32_t*>(ws + OFF_KHC);
  int pm = tid >> 4, pi = (tid & 15)*4;

  // prologue: stage l_lo
  if (l_lo <= l_hi){
    size_t rowb = ((size_t)(l_lo*(l_lo+1))/2 + a)*128 + oh*64;
    #pragma unroll
    for (int t4 = 0; t4 < 4; ++t4){
      int idx4 = t4*256 + tid;
      int ol = idx4 >> 4, i4 = idx4 & 15;
      uint4 v = *reinterpret_cast<const uint4*>(khb + (rowb + ol)*64 + i4*4);
      *reinterpret_cast<uint4*>(sb + ((ol*64 + i4*4) ^ ((ol & 7) << 2))) = v;
    }
    uint32_t a0=0u,a1=0u,a2=0u,a3=0u;
    if (pm <= l_lo){
      const float* xp = ws + OFF_XHAT + (((l_lo*31 + 15 + pm)*8 + b)*128 + pi*2);
      float4 x0 = *reinterpret_cast<const float4*>(xp);
      float4 x1 = *reinterpret_cast<const float4*>(xp + 4);
      a0 = pack2(x0.x,x0.y); a1 = pack2(x0.z,x0.w);
      a2 = pack2(x1.x,x1.y); a3 = pack2(x1.z,x1.w);
    }
    *reinterpret_cast<uint4*>(sb + 4096 + ((pm*64 + pi) ^ ((pm & 7) << 2))) = make_uint4(a0,a1,a2,a3);
  }
  __syncthreads();

  int ol = wv*16 + c;
  for (int l = l_lo; l <= l_hi; ++l){
    bool pf = (l < l_hi);
    uint4 pB[4];
    float4 px0 = make_float4(0.f,0.f,0.f,0.f), px1 = px0;
    bool am = false;
    if (pf){
      int lx = l + 1;
      size_t rowb = ((size_t)(lx*(lx+1))/2 + a)*128 + oh*64;
      #pragma unroll
      for (int t4 = 0; t4 < 4; ++t4){
        int idx4 = t4*256 + tid;
        int o2 = idx4 >> 4, i4 = idx4 & 15;
        pB[t4] = *reinterpret_cast<const uint4*>(khb + (rowb + o2)*64 + i4*4);
      }
      am = (pm <= lx);
      if (am){
        const float* xp = ws + OFF_XHAT + (((lx*31 + 15 + pm)*8 + b)*128 + pi*2);
        px0 = *reinterpret_cast<const float4*>(xp);
        px1 = *reinterpret_cast<const float4*>(xp + 4);
      }
    }
    // compute current l
    frg af[4];
    #pragma unroll
    for (int tt = 0; tt < 4; ++tt)
      af[tt].u = *reinterpret_cast<const uint4*>(sb + 4096 + ((c*64 + tt*16 + g*4) ^ ((c & 7) << 2)));
    f4v ar = {0.f,0.f,0.f,0.f}, ai = {0.f,0.f,0.f,0.f};
    #pragma unroll
    for (int tt = 0; tt < 4; ++tt){
      frg bw;
      bw.u = *reinterpret_cast<const uint4*>(sb + ((ol*64 + tt*16 + g*4) ^ ((ol & 7) << 2)));
      frg br_, bi_;
      #pragma unroll
      for (int j = 0; j < 4; ++j){
        uint32_t w = bw.w[j];
        uint32_t sw = (w >> 16) | (w << 16);
        if (!neg){ br_.w[j] = w ^ 0x80000000u; bi_.w[j] = sw; }
        else if (a & 1){ br_.w[j] = w ^ 0x80008000u; bi_.w[j] = sw ^ 0x80000000u; }
        else { br_.w[j] = w; bi_.w[j] = sw ^ 0x00008000u; }
      }
      ar = __builtin_amdgcn_mfma_f32_16x16x32_bf16(af[tt].s, br_.s, ar, 0, 0, 0);
      ai = __builtin_amdgcn_mfma_f32_16x16x32_bf16(af[tt].s, bi_.s, ai, 0, 0, 0);
    }
    int lq = l - 8*h;
    #pragma unroll
    for (int rr = 0; rr < 4; ++rr){
      int m = g*4 + rr;   // C row=(lane>>4)*4+reg, col=lane&15 (=o in tile)
      zout[(m*64 + ol)*8 + (lq ^ zswz(ol))] = pack2(ar[rr], ai[rr]);
    }
    __syncthreads();
    if (pf){
      #pragma unroll
      for (int t4 = 0; t4 < 4; ++t4){
        int idx4 = t4*256 + tid;
        int o2 = idx4 >> 4, i4 = idx4 & 15;
        *reinterpret_cast<uint4*>(sb + ((o2*64 + i4*4) ^ ((o2 & 7) << 2))) = pB[t4];
      }
      uint32_t a0=0u,a1=0u,a2=0u,a3=0u;
      if (am){
        a0 = pack2(px0.x,px0.y); a1 = pack2(px0.z,px0.w);
        a2 = pack2(px1.x,px1.y); a3 = pack2(px1.z,px1.w);
      }
      *reinterpret_cast<uint4*>(sb + 4096 + ((pm*64 + pi) ^ ((pm & 7) << 2))) = make_uint4(a0,a1,a2,a3);
    }
    __syncthreads();
  }

  // flush zout -> z2 sub-planes [mn][h][bo][l8], dense
  u16t* zr = reinterpret_cast<u16t*>(ws + OFF_Z2);
  u16t* zi = zr + 8126464;
  for (int idx = tid; idx < 1024; idx += 256){
    int m = idx >> 6, o = idx & 63;
    uint32_t v[8];
    #pragma unroll
    for (int lq = 0; lq < 8; ++lq) v[lq] = zout[(m*64 + o)*8 + (lq ^ zswz(o))];
    uint4 reQ = make_uint4((v[0]&0xffffu)|(v[1]<<16), (v[2]&0xffffu)|(v[3]<<16),
                           (v[4]&0xffffu)|(v[5]<<16), (v[6]&0xffffu)|(v[7]<<16));
    uint4 imQ = make_uint4((v[0]>>16)|(v[1]&0xffff0000u), (v[2]>>16)|(v[3]&0xffff0000u),
                           (v[4]>>16)|(v[5]&0xffff0000u), (v[6]>>16)|(v[7]&0xffff0000u));
    size_t base = (size_t)(m*31 + nd)*16384 + (size_t)h*8192 + (size_t)(b*128 + oh*64 + o)*8;
    *reinterpret_cast<uint4*>(zr + base) = reQ;
    *reinterpret_cast<uint4*>(zi + base) = imQ;
  }
}

// MFMA fm+DFT. Block = (bo-tile of 16) x (m). 512 threads.
__global__ __launch_bounds__(512) void k_fmt(float* __restrict__ ws){
  __shared__ uint32_t fmb[16384];       // [nd 32][bok 512] u32 (f16 re,im), swz
  int tid = threadIdx.x;
  int lane = tid & 63, wv = tid >> 6;
  int c = lane & 15, g = lane >> 4;
  int bt = blockIdx.x >> 4, m = blockIdx.x & 15;
  const u16t* z2r = reinterpret_cast<const u16t*>(ws + OFF_Z2);
  const u16t* z2i = z2r + 8126464;
  const u16t* d3b = reinterpret_cast<const u16t*>(ws + OFF_D3);
  const u16t* wtb = reinterpret_cast<const u16t*>(ws + OFF_WT);
  fmb[31*512 + (tid ^ 16)] = 0u;   // zero-pad nd=31 column

  frg wf[2][2][2];
  #pragma unroll
  for (int nt = 0; nt < 2; ++nt)
    #pragma unroll
    for (int p = 0; p < 2; ++p)
      #pragma unroll
      for (int h = 0; h < 2; ++h)
        wf[nt][p][h].u = *reinterpret_cast<const uint4*>(wtb + ((((nt*2+p)*2+h)*16 + c)*32 + g*8));

  // ---- phase A ----
  {
    int hl16 = (g >> 1)*16;
    size_t asub = (size_t)(g & 1)*8192 + (size_t)(bt*16 + c)*8;   // h sub-plane + bo
    int l0 = (g & 1)*8;
    #pragma unroll
    for (int t = 0; t < 4; ++t){
      int nd = wv*4 + t;
      if (nd > 30) break;
      int mn = m*31 + nd;
      frg ar, ai;
      ar.u = *reinterpret_cast<const uint4*>(z2r + (size_t)mn*16384 + asub);
      ai.u = *reinterpret_cast<const uint4*>(z2i + (size_t)mn*16384 + asub);
      int key = ((nd >> 2) & 1) << 4;
      #pragma unroll
      for (int kh = 0; kh < 2; ++kh){
        frg bf;
        bf.u = *reinterpret_cast<const uint4*>(d3b + ((size_t)mn*32 + kh*16 + c)*32 + hl16 + l0);
        f4v z4 = {0.f, 0.f, 0.f, 0.f};
        f4v cre = __builtin_amdgcn_mfma_f32_16x16x32_bf16(ar.s, bf.s, z4, 0, 0, 0);
        f4v cim = __builtin_amdgcn_mfma_f32_16x16x32_bf16(ai.s, bf.s, z4, 0, 0, 0);
        #pragma unroll
        for (int rr = 0; rr < 4; ++rr){
          int bok = (g*4 + rr)*32 + kh*16 + c;
          union { _Float16 hh[2]; uint32_t u; } pk;
          pk.hh[0] = (_Float16)cre[rr];
          pk.hh[1] = (_Float16)cim[rr];
          fmb[nd*512 + (bok ^ key)] = pk.u;
        }
      }
    }
  }
  __syncthreads();
  // ---- phase B ----
  uint32_t* tglob = reinterpret_cast<uint32_t*>(ws) + OFF_T;
  #pragma unroll
  for (int q = 0; q < 4; ++q){
    int mt = wv*4 + q;
    int arow = mt*16 + c;
    frg A0, A1;
    #pragma unroll
    for (int j = 0; j < 4; ++j){
      int nd0 = g*4 + j, nd1 = nd0 + 16;
      A0.w[j] = fmb[nd0*512 + (arow ^ (((nd0 >> 2) & 1) << 4))];
      A1.w[j] = fmb[nd1*512 + (arow ^ (((nd1 >> 2) & 1) << 4))];
    }
    #pragma unroll
    for (int nt = 0; nt < 2; ++nt){
      f4v z4 = {0.f, 0.f, 0.f, 0.f};
      f4v tre = __builtin_amdgcn_mfma_f32_16x16x32_f16(A0.h, wf[nt][0][0].h, z4, 0, 0, 0);
      tre     = __builtin_amdgcn_mfma_f32_16x16x32_f16(A1.h, wf[nt][0][1].h, tre, 0, 0, 0);
      f4v tim = __builtin_amdgcn_mfma_f32_16x16x32_f16(A0.h, wf[nt][1][0].h, z4, 0, 0, 0);
      tim     = __builtin_amdgcn_mfma_f32_16x16x32_f16(A1.h, wf[nt][1][1].h, tim, 0, 0, 0);
      #pragma unroll
      for (int rr = 0; rr < 4; ++rr){
        int bokl = mt*16 + g*4 + rr;
        int bokg = (bt*16 + (bokl >> 5))*32 + (bokl & 31);
        tglob[(size_t)(bokg*16 + m)*32 + nt*16 + c] = pack2(tre[rr], tim[rr]);
      }
    }
  }
}

// out[bok][a][c] = t0.re + sum_{m'=1..15} 2 Re(t[m',c] e^{i 2pi a m'/32}) + bias.
__global__ void k_out(const float* __restrict__ bias, float* __restrict__ out,
                      const float* __restrict__ ws){
  __shared__ uint32_t tl[2048];
  __shared__ float2 tw2[32];
  int tid = threadIdx.x;
  int b4 = blockIdx.x*4;
  const uint32_t* tg = reinterpret_cast<const uint32_t*>(ws) + OFF_T + (size_t)b4*512;
  for (int idx = tid; idx < 2048; idx += 256) tl[idx] = tg[idx];
  if (tid < 32){ double a = 2.0*PI_D*tid/32.0; tw2[tid] = make_float2((float)cos(a), (float)sin(a)); }
  __syncthreads();
  int aq = tid >> 5, c = tid & 31;
  for (int q = 0; q < 4; ++q){
    int bok = b4 + q;
    const uint32_t* tq = tl + q*512;
    float t0r = bf2f(tq[c]);
    float U0=0,U1=0,U2=0,U3=0,V0=0,V1=0,V2=0,V3=0;
    int p = aq;
    #pragma unroll
    for (int m = 1; m < 16; ++m){
      uint32_t wv = tq[m*32 + c];
      float tr = bf2f_lo(wv), ti = bf2f_hi(wv);
      float2 T = tw2[p];
      float u = tr*T.x - ti*T.y;
      float v = tr*T.y + ti*T.x;
      int j = m & 3;
      if      (j == 0){ U0 += u; V0 += v; }
      else if (j == 1){ U1 += u; V1 += v; }
      else if (j == 2){ U2 += u; V2 += v; }
      else            { U3 += u; V3 += v; }
      p = (p + aq) & 31;
    }
    float bia = bias[(bok >> 5) & 127];
    float* op = out + (size_t)bok*1024 + c;
    op[aq*32]      = t0r + 2.f*(U0+U1+U2+U3) + bia;
    op[(aq+8)*32]  = t0r + 2.f*(U0-V1-U2+V3) + bia;
    op[(aq+16)*32] = t0r + 2.f*(U0-U1+U2-U3) + bia;
    op[(aq+24)*32] = t0r + 2.f*(U0+V1-U2-V3) + bia;
  }
}

extern "C" void kernel_launch(void* const* d_in, const int* in_sizes, int n_in,
                              void* d_out, int out_size, void* d_ws, size_t ws_size,
                              hipStream_t stream) {
  const float* x    = (const float*)d_in[0];   // [8,64,64,64]
  const float* kern = (const float*)d_in[1];   // [64,128,32]
  const float* bias = (const float*)d_in[2];   // [128]
  float* out = (float*)d_out;                  // [8,128,32,32,32]
  float* ws  = (float*)d_ws;

  k_zero  <<<dim3(248),  dim3(256), 0, stream>>>(ws);
  k_consts<<<dim3(699),  dim3(256), 0, stream>>>(ws);
  k_xhat  <<<dim3(512),  dim3(256), 0, stream>>>(x, ws);
  k_khc   <<<dim3(2048), dim3(256), 0, stream>>>(kern, ws);
  k_zmt   <<<dim3(992),  dim3(256), 0, stream>>>(ws);
  k_fmt   <<<dim3(1024), dim3(512), 0, stream>>>(ws);
  k_out   <<<dim3(8192), dim3(256), 0, stream>>>(bias, out, ws);
}

// Round 7
// 252.310 us; speedup vs baseline: 1.1819x; 1.1290x over previous
//
#include <hip/hip_runtime.h>
#include <stdint.h>
#include <math.h>

// S2Convolution: BATCH=8, FIN=64, FOUT=128, B_IN=32, B_OUT=16, NL=16, MDIM=31,
// grid 4x8=32, out [8,128,32,32,32] fp32.
//
// v11: revert to verified v8 structure (263.4 us) after two k_zmt fusion
// regressions (v9/v10: occupancy collapse in the serial l-loop structure,
// unexplained by LDS config — abandoned). Banked micro-wins on top of v8:
//  - k_zero folded into k_consts (D3B blocks zero their own (k,l) tile).
//  - k_xhat + k_khc merged into k_xk (block-routed, bodies verbatim).
// Launches 8 -> 6. All math/layout = v8.

#define PI_D 3.14159265358979323846
#define SCALING_F 0.002762135864009951f   // 1/sqrt(32*64*16^4/32^2)

// ws offsets in 4-byte words.
#define OFF_WANA 0            // 16*31*64   = 31744  ([l][m][j] fp32)
#define OFF_FKR  31744        // 32*16*31   = 15872
#define OFF_FKI  47616        // 15872
#define OFF_D3   63488        // 253952 words = 507904 u16 bf16 [mn][k][hl][l]
#define OFF_XHAT 317440       // 16*31*8*64*2 = 507904
#define OFF_WT   317440       // 2048 words = 4096 f16 twiddles (dead xhat rows 0-1)
#define OFF_KHC  825344       // khb bf16 pairs: 136*128*64 = 1114112 u32 words
#define OFF_Z2   3053568      // 2 planes x 496*1024*16 bf16 = 8126464 words ([re|im][mn][bo][l])
#define OFF_T    11180032     // 32768*16*32  = 16777216 u32 (t bf16-pairs)
                              // Z3 aliases first 4194304 words (dead once k_fmt writes t)
// total = 27957248 words = 112 MB

typedef unsigned short u16t;
typedef __attribute__((ext_vector_type(8))) short s8v;       // 8 bf16
typedef __attribute__((ext_vector_type(8))) _Float16 h8v;    // 8 f16
typedef __attribute__((ext_vector_type(4))) float f4v;

union frg { uint4 u; uint32_t w[4]; s8v s; h8v h; };

__device__ inline double ipow_d(double x, int e){
  double r = 1.0;
  while (e > 0){ if (e & 1) r *= x; x *= x; e >>= 1; }
  return r;
}

// Wigner small-d d^l_{m1,m2}(beta), fp64, matches reference _wigner_d
__device__ double wig_d(int l, int m1, int m2, double beta, const double* LF){
  double c = cos(0.5*beta), s = sin(0.5*beta);
  double sum = 0.0;
  for (int k = 0; k <= 2*l; ++k){
    int a1 = l + m2 - k, a3 = m1 - m2 + k, a4 = l - m1 - k;
    if (a1 < 0 || a3 < 0 || a4 < 0) continue;
    double logc = 0.5*(LF[l+m1]+LF[l-m1]+LF[l+m2]+LF[l-m2]) - LF[a1] - LF[k] - LF[a3] - LF[a4];
    double t = exp(logc) * ipow_d(c, a1 + a4) * ipow_d(s, a3 + k);
    sum += (a3 & 1) ? -t : t;  // (-1)^(m1-m2+k)
  }
  return sum;
}

__device__ inline uint32_t f2bf(float f){
  uint32_t u = __float_as_uint(f);
  return (u + 0x7fffu + ((u >> 16) & 1u)) >> 16;   // RNE
}
__device__ inline float bf2f(uint32_t h){ return __uint_as_float((h & 0xffffu) << 16); }
__device__ inline float bf2f_lo(uint32_t h){ return __uint_as_float(h << 16); }
__device__ inline float bf2f_hi(uint32_t h){ return __uint_as_float(h & 0xffff0000u); }
__device__ inline uint32_t pack2(float a, float b){ return f2bf(a) | (f2bf(b) << 16); }

#define LF_INIT \
  __shared__ double LF[40]; \
  if (threadIdx.x == 0){ LF[0] = 0.0; double acc_ = 0.0; for (int n_ = 1; n_ < 40; ++n_){ acc_ += log((double)n_); LF[n_] = acc_; } } \
  __syncthreads();

// Merged constant tables: blocks [0,124) wana, [124,186) fk, [186,698) dsyn->D3B
// (each D3B block zeroes its own (k,l) tile first — replaces k_zero), 698 Wt.
__global__ void k_consts(float* __restrict__ ws){
  LF_INIT
  int bid = blockIdx.x, tid = threadIdx.x;
  if (bid < 124){
    // Driscoll-Healy weights: wsum depends only on j; each block spans <=2 j.
    __shared__ double wj2[2];
    int id0 = bid*256;
    int jbase = id0/496;
    if (tid < 2){
      int j = jbase + tid;
      double wv_ = 0.0;
      if (j < 64){
        double beta = PI_D*(2*j + 0.5)/128.0;
        double wsum = 0.0;
        for (int kk = 0; kk < 32; ++kk) wsum += sin(beta*(2*kk+1))/(double)(2*kk+1);
        wv_ = (2.0*PI_D/64.0)*(2.0/32.0)*sin(beta)*wsum;
      }
      wj2[tid] = wv_;
    }
    __syncthreads();
    int id = id0 + tid;
    int m = id % 31, l = (id / 31) & 15, j = id / 496;
    int mp = m - 15, amp = mp < 0 ? -mp : mp;
    float val = 0.f;
    if (amp <= l){
      double beta = PI_D*(2*j + 0.5)/128.0;
      val = (float)(wj2[j - jbase] * wig_d(l, mp, 0, beta, LF));
    }
    ws[OFF_WANA + (l*31 + m)*64 + j] = val;   // [l][m][j]
  } else if (bid < 186){
    int id = (bid - 124)*256 + tid;
    if (id >= 15872) return;
    int n = id % 31, l = (id / 31) & 15, g = id / 496;
    int np = n - 15, anp = np < 0 ? -np : np;
    float vr = 0.f, vi = 0.f;
    if (anp <= l){
      double beta = PI_D*((double)((g >> 3) + 1))/32.0;
      double alpha = (PI_D/4.0)*(double)(g & 7);
      double d = wig_d(l, np, 0, beta, LF);
      vr = (float)(d*cos(np*alpha));
      vi = (float)(d*sin(np*alpha));
    }
    ws[OFF_FKR + id] = vr;
    ws[OFF_FKI + id] = vi;
  } else if (bid < 698){
    // D3B[mn][k][hl][l] bf16 hi/lo: (2l+1)*wig_d in B-fragment layout.
    int bb = bid - 186;
    int k = bb >> 4, l = bb & 15;
    u16t* d3b = reinterpret_cast<u16t*>(ws + OFF_D3);
    // zero own (k,l) tile (all mn, both hl planes) — replaces k_zero
    for (int mn = tid; mn < 496; mn += 256){
      d3b[(mn*32 + k)*32 + l]      = 0;
      d3b[(mn*32 + k)*32 + 16 + l] = 0;
    }
    __syncthreads();
    int n21 = 2*l + 1, items = (l+1)*n21;
    double beta = PI_D*(2*k + 0.5)/64.0;
    float fl = (float)(2*l + 1);
    for (int item = tid; item < items; item += 256){
      int im = item / n21, in = item - (item/n21)*n21;
      int mn = im*31 + in - l + 15;
      float v = fl * (float)wig_d(l, im, in - l, beta, LF);
      uint32_t hb = f2bf(v);
      uint32_t lb = f2bf(v - bf2f(hb));
      d3b[(mn*32 + k)*32 + l]      = (u16t)hb;
      d3b[(mn*32 + k)*32 + 16 + l] = (u16t)lb;
    }
  } else {
    // Wt[nt][p][h][c][kidx] f16: B-fragment twiddles for the n-DFT.
    u16t* wt = reinterpret_cast<u16t*>(ws + OFF_WT);
    for (int idx = tid; idx < 4096; idx += 256){
      int kidx = idx & 31, cc = (idx >> 5) & 15, h = (idx >> 9) & 1;
      int p = (idx >> 10) & 1, nt = (idx >> 11) & 1;
      int q = kidx & 1, nloc = kidx >> 1, n = h*16 + nloc, cg = nt*16 + cc;
      float val = 0.f;
      if (n <= 30){
        double th = 2.0*PI_D*(double)(((17 + n)*cg) & 31)/32.0;
        float wr = (float)cos(th), wi = (float)sin(th);
        val = p ? (q ? wr : wi) : (q ? -wi : wr);
      }
      union { _Float16 hh[2]; u16t us[2]; } cv;
      cv.hh[0] = (_Float16)val; cv.hh[1] = (_Float16)0.f;
      wt[idx] = cv.us[0];
    }
  }
}

// Merged k_xhat (bid<512) + k_khc (bid>=512). Bodies verbatim from v8.
// xhat[l][m=15+m'][b][i] (cpx fp32), rows>=15 only.
// khb[row=tri(l)+np][o][i] u32 = (bf16 re,im) of SCALING*sum_g kern*conj(FK).
__global__ __launch_bounds__(256) void k_xk(const float* __restrict__ x,
                                            const float* __restrict__ kern,
                                            float* __restrict__ ws){
  __shared__ float smem[6272];
  int tid = threadIdx.x;
  if (blockIdx.x < 512){
    float* xl  = smem;          // 4096
    float* c64 = smem + 4096;   // 64
    float* s64 = smem + 4160;   // 64
    float* xmr = smem + 4224;   // 1024
    float* xmi = smem + 5248;   // 1024
    int b = blockIdx.x >> 6, i = blockIdx.x & 63;
    const float* xp = x + (b*64 + i)*4096;
    for (int idx = tid; idx < 4096; idx += 256) xl[idx] = xp[idx];
    if (tid < 64){ double a = 2.0*PI_D*tid/64.0; c64[tid] = (float)cos(a); s64[tid] = (float)sin(a); }
    __syncthreads();
    for (int item = tid; item < 1024; item += 256){
      int j = item >> 4, mi = item & 15;
      float re = 0.f, im = 0.f;
      const float* xr = xl + j*64;
      for (int a = 0; a < 64; ++a){
        int p = (mi*a) & 63;
        re += xr[a]*c64[p];
        im -= xr[a]*s64[p];
      }
      xmr[item] = re; xmi[item] = im;
    }
    __syncthreads();
    {
      int l = tid >> 4, mi = tid & 15;
      if (mi <= l){
        float rr = 0.f, ri = 0.f;
        const float* wrow = ws + OFF_WANA + (l*31 + 15 + mi)*64;   // dense j-row
        for (int j = 0; j < 64; ++j){
          float w = wrow[j];
          rr += w * xmr[j*16 + mi];
          ri += w * xmi[j*16 + mi];
        }
        int dst = OFF_XHAT + ((l*31 + 15 + mi)*8 + b)*128 + i*2;
        ws[dst] = rr; ws[dst+1] = ri;
      }
    }
  } else {
    float* kl2 = smem;          // 32*66 = 2112
    float* fr  = smem + 2112;   // 992
    float* fi  = smem + 3104;   // 992
    int bb = blockIdx.x - 512;
    int o = bb >> 4, l = bb & 15;
    for (int idx = tid; idx < 2048; idx += 256){
      int i = idx >> 5, g = idx & 31;
      kl2[g*66 + i] = kern[(i*128 + o)*32 + g];
    }
    for (int idx = tid; idx < 992; idx += 256){
      int g = idx / 31, n = idx - (idx/31)*31;
      fr[idx] = ws[OFF_FKR + g*496 + l*31 + n];
      fi[idx] = ws[OFF_FKI + g*496 + l*31 + n];
    }
    __syncthreads();
    uint32_t* khb = reinterpret_cast<uint32_t*>(ws + OFF_KHC);
    int c1 = (l*(l+1)) >> 1;
    int ntask = (l+1)*32;
    for (int t = tid; t < ntask; t += 256){
      int np = t >> 5, ip = t & 31, i0 = 2*ip;
      float ar0=0.f, ai0=0.f, ar1=0.f, ai1=0.f;
      for (int g = 0; g < 32; ++g){
        float2 kv = *reinterpret_cast<const float2*>(kl2 + g*66 + i0);
        float fv = fr[g*31 + 15 + np], gv = fi[g*31 + 15 + np];
        ar0 += kv.x*fv; ai0 -= kv.x*gv;
        ar1 += kv.y*fv; ai1 -= kv.y*gv;
      }
      size_t base = (size_t)((c1 + np)*128 + o)*64 + i0;
      khb[base]     = pack2(SCALING_F*ar0, SCALING_F*ai0);
      khb[base + 1] = pack2(SCALING_F*ar1, SCALING_F*ai1);
    }
  }
}

// MFMA z: block (b, l, np). z[m][o] = sum_i xhat[l,m,b,i]*khb[l,np,o,i] (cpx),
// plus the -np variant via sign masks. A=xhat K-interleaved bf16 (m>l zeroed),
// B=khb frags derived in-register. Out: Z3[b][r][m][o] u32 (re,im bf16).
__global__ __launch_bounds__(256) void k_zm(float* __restrict__ ws){
  __shared__ uint32_t lds_a[1024];   // [m16][i64] cpx pairs, 16B-group XOR swz
  __shared__ uint32_t lds_b[8192];   // [o128][i64] cpx pairs, swz
  int tid = threadIdx.x, lane = tid & 63, wv = tid >> 6;
  int c = lane & 15, g = lane >> 4;
  int bid = blockIdx.x;
  int b = bid / 136, t = bid - b*136;
  int l = (int)((sqrtf(8.f*(float)t + 1.f) - 1.f)*0.5f);
  while ((l+1)*(l+2)/2 <= t) ++l;
  while (l*(l+1)/2 > t) --l;
  int np = t - l*(l+1)/2;

  // stage A: xhat rows m=0..l (m>l zeroed)
  for (int idx = tid; idx < 1024; idx += 256){
    int m = idx >> 6, i = idx & 63;
    uint32_t v = 0u;
    if (m <= l){
      const float* xp = ws + OFF_XHAT + (((l*31 + 15 + m)*8 + b)*128 + 2*i);
      float2 xv = *reinterpret_cast<const float2*>(xp);
      v = pack2(xv.x, xv.y);
    }
    lds_a[(m*64 + i) ^ ((m & 7) << 2)] = v;
  }
  // stage B: khb row (l,np), 128 o x 64 i
  {
    const uint32_t* khb = reinterpret_cast<const uint32_t*>(ws + OFF_KHC);
    size_t rowbase = (size_t)((l*(l+1))/2 + np)*128;
    for (int idx4 = tid; idx4 < 2048; idx4 += 256){
      int o = idx4 >> 4, i4 = idx4 & 15;
      uint4 v = *reinterpret_cast<const uint4*>(khb + (rowbase + o)*64 + i4*4);
      *reinterpret_cast<uint4*>(lds_b + ((o*64 + i4*4) ^ ((o & 7) << 2))) = v;
    }
  }
  __syncthreads();

  // A-frags (same for all o-tiles): t-chunk tt covers cpx i = 16*tt + 4*g .. +3
  frg af[4];
  #pragma unroll
  for (int tt = 0; tt < 4; ++tt)
    af[tt].u = *reinterpret_cast<const uint4*>(lds_a + ((c*64 + tt*16 + g*4) ^ ((c & 7) << 2)));

  uint32_t* z3 = reinterpret_cast<uint32_t*>(ws) + OFF_T;   // Z3 alias
  int rpos = l*l + l + np, rneg = l*l + l - np;
  for (int ot = wv; ot < 8; ot += 4){
    f4v arp = {0.f,0.f,0.f,0.f}, aip = {0.f,0.f,0.f,0.f};
    f4v arn = {0.f,0.f,0.f,0.f}, ain = {0.f,0.f,0.f,0.f};
    int oc = ot*16 + c;
    #pragma unroll
    for (int tt = 0; tt < 4; ++tt){
      frg bw;
      bw.u = *reinterpret_cast<const uint4*>(lds_b + ((oc*64 + tt*16 + g*4) ^ ((oc & 7) << 2)));
      frg brp, bip;
      #pragma unroll
      for (int j = 0; j < 4; ++j){
        uint32_t w = bw.w[j];
        uint32_t sw = (w >> 16) | (w << 16);
        brp.w[j] = w ^ 0x80000000u;    // [kr, -ki]
        bip.w[j] = sw;                 // [ki,  kr]
      }
      arp = __builtin_amdgcn_mfma_f32_16x16x32_bf16(af[tt].s, brp.s, arp, 0, 0, 0);
      aip = __builtin_amdgcn_mfma_f32_16x16x32_bf16(af[tt].s, bip.s, aip, 0, 0, 0);
      if (np){
        frg brn, bin;
        #pragma unroll
        for (int j = 0; j < 4; ++j){
          uint32_t w = bw.w[j];
          uint32_t sw = (w >> 16) | (w << 16);
          if (np & 1){ brn.w[j] = w ^ 0x80008000u; bin.w[j] = sw ^ 0x80000000u; }
          else       { brn.w[j] = w;               bin.w[j] = sw ^ 0x00008000u; }
        }
        arn = __builtin_amdgcn_mfma_f32_16x16x32_bf16(af[tt].s, brn.s, arn, 0, 0, 0);
        ain = __builtin_amdgcn_mfma_f32_16x16x32_bf16(af[tt].s, bin.s, ain, 0, 0, 0);
      }
    }
    #pragma unroll
    for (int rr = 0; rr < 4; ++rr){
      int m = g*4 + rr;   // C row=(lane>>4)*4+reg, col=lane&15
      z3[((size_t)(b*256 + rpos)*16 + m)*128 + oc] = pack2(arp[rr], aip[rr]);
      if (np)
        z3[((size_t)(b*256 + rneg)*16 + m)*128 + oc] = pack2(arn[rr], ain[rr]);
    }
  }
}

// Z3[b][r][m][o] -> zr/zi planes [mn][bo][l] u16 (k_fmt's layout), zero-padding
// invalid l<|n'| slots. Block = (b, m, o-quarter). LDS transpose, dense writes.
__global__ __launch_bounds__(256) void k_tr(float* __restrict__ ws){
  __shared__ uint32_t zl[256*33];   // [r][o32], +1 pad -> conflict-free l-gather
  int tid = threadIdx.x, bid = blockIdx.x;
  int b = bid >> 6, m = (bid >> 2) & 15, h = bid & 3;
  const uint32_t* z3 = reinterpret_cast<const uint32_t*>(ws) + OFF_T;
  for (int idx = tid; idx < 8192; idx += 256){
    int r = idx >> 5, o = idx & 31;
    zl[r*33 + o] = z3[((size_t)(b*256 + r)*16 + m)*128 + h*32 + o];
  }
  __syncthreads();
  u16t* zr = reinterpret_cast<u16t*>(ws + OFF_Z2);
  u16t* zi = zr + 8126464;
  for (int task = tid; task < 992; task += 256){
    int nd = task >> 5, o = task & 31;     // o inner -> dense 32B-run writes
    int ndp = nd - 15, a = ndp < 0 ? -ndp : ndp;
    uint32_t re[8], im[8];
    #pragma unroll
    for (int j = 0; j < 8; ++j){
      uint32_t r0 = 0u, i0 = 0u, r1 = 0u, i1 = 0u;
      int l0 = 2*j, l1 = 2*j + 1;
      if (l0 >= a){ uint32_t v = zl[(l0*l0 + l0 + ndp)*33 + o]; r0 = v & 0xffffu; i0 = v >> 16; }
      if (l1 >= a){ uint32_t v = zl[(l1*l1 + l1 + ndp)*33 + o]; r1 = v & 0xffffu; i1 = v >> 16; }
      re[j] = r0 | (r1 << 16); im[j] = i0 | (i1 << 16);
    }
    size_t base = (size_t)(m*31 + nd)*16384 + (size_t)(b*128 + h*32 + o)*16;
    *reinterpret_cast<uint4*>(zr + base)     = make_uint4(re[0],re[1],re[2],re[3]);
    *reinterpret_cast<uint4*>(zr + base + 8) = make_uint4(re[4],re[5],re[6],re[7]);
    *reinterpret_cast<uint4*>(zi + base)     = make_uint4(im[0],im[1],im[2],im[3]);
    *reinterpret_cast<uint4*>(zi + base + 8) = make_uint4(im[4],im[5],im[6],im[7]);
  }
}

// MFMA fm+DFT. Block = (bo-tile of 16) x (m). 512 threads.
__global__ __launch_bounds__(512) void k_fmt(float* __restrict__ ws){
  __shared__ uint32_t fmb[16384];       // [nd 32][bok 512] u32 (f16 re,im), swz
  int tid = threadIdx.x;
  int lane = tid & 63, wv = tid >> 6;
  int c = lane & 15, g = lane >> 4;
  int bt = blockIdx.x >> 4, m = blockIdx.x & 15;
  const u16t* z2r = reinterpret_cast<const u16t*>(ws + OFF_Z2);
  const u16t* z2i = z2r + 8126464;
  const u16t* d3b = reinterpret_cast<const u16t*>(ws + OFF_D3);
  const u16t* wtb = reinterpret_cast<const u16t*>(ws + OFF_WT);
  fmb[31*512 + (tid ^ 16)] = 0u;   // zero-pad nd=31 column

  frg wf[2][2][2];
  #pragma unroll
  for (int nt = 0; nt < 2; ++nt)
    #pragma unroll
    for (int p = 0; p < 2; ++p)
      #pragma unroll
      for (int h = 0; h < 2; ++h)
        wf[nt][p][h].u = *reinterpret_cast<const uint4*>(wtb + ((((nt*2+p)*2+h)*16 + c)*32 + g*8));

  // ---- phase A ----
  {
    int l0 = (g & 1)*8;
    int hl16 = (g >> 1)*16;
    size_t bo16 = (size_t)(bt*16 + c)*16;
    #pragma unroll
    for (int t = 0; t < 4; ++t){
      int nd = wv*4 + t;
      if (nd > 30) break;
      int mn = m*31 + nd;
      frg ar, ai;
      ar.u = *reinterpret_cast<const uint4*>(z2r + (size_t)mn*16384 + bo16 + l0);
      ai.u = *reinterpret_cast<const uint4*>(z2i + (size_t)mn*16384 + bo16 + l0);
      int key = ((nd >> 2) & 1) << 4;
      #pragma unroll
      for (int kh = 0; kh < 2; ++kh){
        frg bf;
        bf.u = *reinterpret_cast<const uint4*>(d3b + ((size_t)mn*32 + kh*16 + c)*32 + hl16 + l0);
        f4v z4 = {0.f, 0.f, 0.f, 0.f};
        f4v cre = __builtin_amdgcn_mfma_f32_16x16x32_bf16(ar.s, bf.s, z4, 0, 0, 0);
        f4v cim = __builtin_amdgcn_mfma_f32_16x16x32_bf16(ai.s, bf.s, z4, 0, 0, 0);
        #pragma unroll
        for (int rr = 0; rr < 4; ++rr){
          int bok = (g*4 + rr)*32 + kh*16 + c;
          union { _Float16 hh[2]; uint32_t u; } pk;
          pk.hh[0] = (_Float16)cre[rr];
          pk.hh[1] = (_Float16)cim[rr];
          fmb[nd*512 + (bok ^ key)] = pk.u;
        }
      }
    }
  }
  __syncthreads();
  // ---- phase B ----
  uint32_t* tglob = reinterpret_cast<uint32_t*>(ws) + OFF_T;
  #pragma unroll
  for (int q = 0; q < 4; ++q){
    int mt = wv*4 + q;
    int arow = mt*16 + c;
    frg A0, A1;
    #pragma unroll
    for (int j = 0; j < 4; ++j){
      int nd0 = g*4 + j, nd1 = nd0 + 16;
      A0.w[j] = fmb[nd0*512 + (arow ^ (((nd0 >> 2) & 1) << 4))];
      A1.w[j] = fmb[nd1*512 + (arow ^ (((nd1 >> 2) & 1) << 4))];
    }
    #pragma unroll
    for (int nt = 0; nt < 2; ++nt){
      f4v z4 = {0.f, 0.f, 0.f, 0.f};
      f4v tre = __builtin_amdgcn_mfma_f32_16x16x32_f16(A0.h, wf[nt][0][0].h, z4, 0, 0, 0);
      tre     = __builtin_amdgcn_mfma_f32_16x16x32_f16(A1.h, wf[nt][0][1].h, tre, 0, 0, 0);
      f4v tim = __builtin_amdgcn_mfma_f32_16x16x32_f16(A0.h, wf[nt][1][0].h, z4, 0, 0, 0);
      tim     = __builtin_amdgcn_mfma_f32_16x16x32_f16(A1.h, wf[nt][1][1].h, tim, 0, 0, 0);
      #pragma unroll
      for (int rr = 0; rr < 4; ++rr){
        int bokl = mt*16 + g*4 + rr;
        int bokg = (bt*16 + (bokl >> 5))*32 + (bokl & 31);
        tglob[(size_t)(bokg*16 + m)*32 + nt*16 + c] = pack2(tre[rr], tim[rr]);
      }
    }
  }
}

// out[bok][a][c] = t0.re + sum_{m'=1..15} 2 Re(t[m',c] e^{i 2pi a m'/32}) + bias.
__global__ void k_out(const float* __restrict__ bias, float* __restrict__ out,
                      const float* __restrict__ ws){
  __shared__ uint32_t tl[2048];
  __shared__ float2 tw2[32];
  int tid = threadIdx.x;
  int b4 = blockIdx.x*4;
  const uint32_t* tg = reinterpret_cast<const uint32_t*>(ws) + OFF_T + (size_t)b4*512;
  for (int idx = tid; idx < 2048; idx += 256) tl[idx] = tg[idx];
  if (tid < 32){ double a = 2.0*PI_D*tid/32.0; tw2[tid] = make_float2((float)cos(a), (float)sin(a)); }
  __syncthreads();
  int aq = tid >> 5, c = tid & 31;
  for (int q = 0; q < 4; ++q){
    int bok = b4 + q;
    const uint32_t* tq = tl + q*512;
    float t0r = bf2f(tq[c]);
    float U0=0,U1=0,U2=0,U3=0,V0=0,V1=0,V2=0,V3=0;
    int p = aq;
    #pragma unroll
    for (int m = 1; m < 16; ++m){
      uint32_t wv = tq[m*32 + c];
      float tr = bf2f_lo(wv), ti = bf2f_hi(wv);
      float2 T = tw2[p];
      float u = tr*T.x - ti*T.y;
      float v = tr*T.y + ti*T.x;
      int j = m & 3;
      if      (j == 0){ U0 += u; V0 += v; }
      else if (j == 1){ U1 += u; V1 += v; }
      else if (j == 2){ U2 += u; V2 += v; }
      else            { U3 += u; V3 += v; }
      p = (p + aq) & 31;
    }
    float bia = bias[(bok >> 5) & 127];
    float* op = out + (size_t)bok*1024 + c;
    op[aq*32]      = t0r + 2.f*(U0+U1+U2+U3) + bia;
    op[(aq+8)*32]  = t0r + 2.f*(U0-V1-U2+V3) + bia;
    op[(aq+16)*32] = t0r + 2.f*(U0-U1+U2-U3) + bia;
    op[(aq+24)*32] = t0r + 2.f*(U0+V1-U2-V3) + bia;
  }
}

extern "C" void kernel_launch(void* const* d_in, const int* in_sizes, int n_in,
                              void* d_out, int out_size, void* d_ws, size_t ws_size,
                              hipStream_t stream) {
  const float* x    = (const float*)d_in[0];   // [8,64,64,64]
  const float* kern = (const float*)d_in[1];   // [64,128,32]
  const float* bias = (const float*)d_in[2];   // [128]
  float* out = (float*)d_out;                  // [8,128,32,32,32]
  float* ws  = (float*)d_ws;

  k_consts<<<dim3(699),  dim3(256), 0, stream>>>(ws);
  k_xk    <<<dim3(2560), dim3(256), 0, stream>>>(x, kern, ws);
  k_zm    <<<dim3(1088), dim3(256), 0, stream>>>(ws);
  k_tr    <<<dim3(512),  dim3(256), 0, stream>>>(ws);
  k_fmt   <<<dim3(1024), dim3(512), 0, stream>>>(ws);
  k_out   <<<dim3(8192), dim3(256), 0, stream>>>(bias, out, ws);
}